// Round 13
// baseline (173.373 us; speedup 1.0000x reference)
//
#include <hip/hip_runtime.h>
#include <hip/hip_bf16.h>

typedef __bf16 bf16x8 __attribute__((ext_vector_type(8)));
typedef __bf16 bf16x4 __attribute__((ext_vector_type(4)));
typedef float f32x2 __attribute__((ext_vector_type(2)));
typedef float f32x4 __attribute__((ext_vector_type(4)));
typedef float f32x16 __attribute__((ext_vector_type(16)));

#define B_ 2
#define L_ 2048
#define D_ 1024
#define H_ 16
#define DK_ 64

// 0.125 (1/sqrt(DK)) * log2(e): folded into Q so P = exp2(S^T) directly.
#define QSCALE 0.180336880f

// Raw HW exp2 (R12: -14.3us on attn — OCML fixup was the hidden VALU mass).
#if __has_builtin(__builtin_amdgcn_exp2f)
#define EXP2(x) __builtin_amdgcn_exp2f(x)
#else
extern "C" __device__ float __ocml_native_exp2_f32(float);
#define EXP2(x) __ocml_native_exp2_f32(x)
#endif

__device__ __forceinline__ __bf16 f2bf(float f) { return (__bf16)f; }

// ---------- fused prep: x->bf16, w_qkv->T bf16, w_out->T bf16 ----------
__global__ __launch_bounds__(256) void prep(const float* __restrict__ x,
                                            const float* __restrict__ w_qkv,
                                            const float* __restrict__ w_out,
                                            __bf16* __restrict__ xb,
                                            __bf16* __restrict__ wqkvT,
                                            __bf16* __restrict__ woutT) {
  __shared__ float ts[32][33];
  const int blk = blockIdx.x;
  const int tid = threadIdx.x;
  if (blk < 2048) {
    const int i = blk * 2048 + tid * 8;
    const float4 a = *(const float4*)&x[i];
    const float4 b = *(const float4*)&x[i + 4];
    bf16x8 o;
    o[0] = f2bf(a.x); o[1] = f2bf(a.y); o[2] = f2bf(a.z); o[3] = f2bf(a.w);
    o[4] = f2bf(b.x); o[5] = f2bf(b.y); o[6] = f2bf(b.z); o[7] = f2bf(b.w);
    *(bf16x8*)&xb[i] = o;
    return;
  }
  const float* W;
  __bf16* WT;
  int N, t;
  if (blk < 5120) { t = blk - 2048; N = 3 * D_; W = w_qkv; WT = wqkvT; }
  else            { t = blk - 5120; N = D_;     W = w_out; WT = woutT; }
  const int nblk = N / 32;
  const int nt = (t % nblk) * 32, kt = (t / nblk) * 32;
  const int K = D_;
  const int r = tid >> 3, c4 = (tid & 7) * 4;
  const float4 v = *(const float4*)&W[(size_t)(kt + r) * N + nt + c4];
  ts[r][c4 + 0] = v.x; ts[r][c4 + 1] = v.y; ts[r][c4 + 2] = v.z; ts[r][c4 + 3] = v.w;
  __syncthreads();
  bf16x4 o;
  o[0] = f2bf(ts[c4 + 0][r]); o[1] = f2bf(ts[c4 + 1][r]);
  o[2] = f2bf(ts[c4 + 2][r]); o[3] = f2bf(ts[c4 + 3][r]);
  *(bf16x4*)&WT[(size_t)(nt + r) * K + kt + c4] = o;
}

// ---------- m97-style GEMM (QKV): C = A @ BT^T + bias, split epilogue ----------
// 128x128 tile, BK=64 + T2 source-side XOR swizzle (conflict-free frag reads).
__global__ __launch_bounds__(256) void gemm_qkv(const __bf16* __restrict__ A,
                                                const __bf16* __restrict__ BT,
                                                const float* __restrict__ bias,
                                                __bf16* __restrict__ Qp,
                                                __bf16* __restrict__ Kp,
                                                __bf16* __restrict__ Vp,
                                                int M, int N, int K) {
  __shared__ __align__(16) __bf16 smem_bf[17408];

  const int tid  = threadIdx.x;
  const int wave = tid >> 6, lane = tid & 63, quad = lane >> 4, l16 = lane & 15;
  const int wr = wave >> 1, wc = wave & 1;
  const int m0 = blockIdx.y * 128, n0 = blockIdx.x * 128;
  const int s8 = l16 & 7;                 // frag-row swizzle key (row&7 == l16&7)

  f32x4 acc[4][4];
#pragma unroll
  for (int i = 0; i < 4; ++i)
#pragma unroll
    for (int j = 0; j < 4; ++j) acc[i][j] = (f32x4){0.f, 0.f, 0.f, 0.f};

  for (int k0 = 0; k0 < K; k0 += 64) {
    __syncthreads();
#pragma unroll
    for (int p = 0; p < 4; ++p) {
      const int c = p * 256 + tid;          // 1024 chunks of 16B per tile
      const int row = c >> 3, kc = c & 7;   // 8 chunks per 128B row
      const int src = kc ^ (row & 7);       // inverse-swizzled global chunk
      __builtin_amdgcn_global_load_lds(
          (const __attribute__((address_space(1))) void*)&A[(size_t)(m0 + row) * K + k0 + src * 8],
          (__attribute__((address_space(3))) void*)&smem_bf[c * 8], 16, 0, 0);
      __builtin_amdgcn_global_load_lds(
          (const __attribute__((address_space(1))) void*)&BT[(size_t)(n0 + row) * K + k0 + src * 8],
          (__attribute__((address_space(3))) void*)&smem_bf[8192 + c * 8], 16, 0, 0);
    }
    __syncthreads();

#pragma unroll
    for (int ks = 0; ks < 2; ++ks) {
      const int ca = ((ks * 4 + quad) ^ s8) << 3;   // physical chunk offset
      bf16x8 af[4], bfr[4];
#pragma unroll
      for (int mt = 0; mt < 4; ++mt)
        af[mt] = *(const bf16x8*)&smem_bf[(wr * 64 + mt * 16 + l16) * 64 + ca];
#pragma unroll
      for (int nt = 0; nt < 4; ++nt)
        bfr[nt] = *(const bf16x8*)&smem_bf[8192 + (wc * 64 + nt * 16 + l16) * 64 + ca];
#pragma unroll
      for (int mt = 0; mt < 4; ++mt)
#pragma unroll
        for (int nt = 0; nt < 4; ++nt)
          acc[mt][nt] = __builtin_amdgcn_mfma_f32_16x16x32_bf16(af[mt], bfr[nt], acc[mt][nt], 0, 0, 0);
    }
  }

  const int sec  = (n0 + wc * 64) >> 6;   // 64-col section, 0..47
  const int type = sec % 3;               // 0=Q, 1=K, 2=V
  const int hh   = sec / 3;               // head
  const int row0 = m0 + wr * 64;
  const int bb   = row0 >> 11;
  const int tok0 = row0 & (L_ - 1);
  const size_t bh = (size_t)bb * H_ + hh;
  float bvv[4];
#pragma unroll
  for (int nt = 0; nt < 4; ++nt) bvv[nt] = bias[n0 + wc * 64 + nt * 16 + l16];

  __syncthreads();                        // all waves done reading As/Bs
  __bf16* epi = smem_bf + wave * 4352;    // 64 rows x 68 elems, per-wave

  if (type == 2) {
#pragma unroll
    for (int nt = 0; nt < 4; ++nt) {
      const int d = nt * 16 + l16;
#pragma unroll
      for (int mt = 0; mt < 4; ++mt) {
        bf16x4 t;
#pragma unroll
        for (int r = 0; r < 4; ++r) t[r] = f2bf(acc[mt][nt][r] + bvv[nt]);
        *(bf16x4*)&epi[d * 68 + mt * 16 + quad * 4] = t;
      }
    }
  } else {
    const float sc = (type == 0) ? QSCALE : 1.0f;
#pragma unroll
    for (int nt = 0; nt < 4; ++nt)
#pragma unroll
      for (int mt = 0; mt < 4; ++mt)
#pragma unroll
        for (int r = 0; r < 4; ++r)
          epi[(mt * 16 + quad * 4 + r) * 68 + nt * 16 + l16] =
              f2bf((acc[mt][nt][r] + bvv[nt]) * sc);
  }
  asm volatile("s_waitcnt lgkmcnt(0)" ::: "memory");

  __bf16* dst = (type == 0 ? Qp : type == 1 ? Kp : Vp) + (bh * L_ + tok0) * 64;
  const int swzm = (type == 0) ? 0 : 7;
#pragma unroll
  for (int i = 0; i < 8; ++i) {
    const int c = i * 64 + lane;
    const int row = c >> 3, cc = c & 7;
    const int gcc = cc ^ (row & swzm);
    const __bf16* lp = epi + row * 68 + cc * 8;
    int2 lo = *(const int2*)lp;
    int2 hi = *(const int2*)(lp + 4);
    int4 v; v.x = lo.x; v.y = lo.y; v.z = hi.x; v.w = hi.y;
    *(int4*)(dst + (size_t)row * 64 + gcc * 8) = v;
  }
}

// ---------- output-projection GEMM: 128(M)x64(N) tile, 512 thr, BK=64 ----------
// R13: same occupancy as the 64^2 version (512 blocks x 8 waves = 16 waves/CU
// = 4/SIMD) but staging bytes and barrier events per FLOP halve (24KB staged
// per k-iter feeds 64 wave-MFMAs vs 16KB for 32). T2 source-side XOR swizzle
// (conflict-free reads, row&7 == l16&7). LDS 24KB, VGPR ~64.
__global__ __launch_bounds__(512) void gemm_bt64(const __bf16* __restrict__ A,
                                                 const __bf16* __restrict__ BT,
                                                 const float* __restrict__ bias,
                                                 float* __restrict__ C,
                                                 int M, int N, int K) {
  __shared__ __align__(16) __bf16 As[128 * 64];  // [m][k], chunk-swizzled
  __shared__ __align__(16) __bf16 Bs[64 * 64];   // [n][k], chunk-swizzled

  const int tid  = threadIdx.x;
  const int wave = tid >> 6, lane = tid & 63, quad = lane >> 4, l16 = lane & 15;
  const int m0 = blockIdx.y * 128, n0 = blockIdx.x * 64;
  const int s8 = l16 & 7;                 // read-row swizzle key (rows = x*16+l16)

  f32x4 acc[4];
  acc[0] = acc[1] = acc[2] = acc[3] = (f32x4){0.f, 0.f, 0.f, 0.f};

  for (int k0 = 0; k0 < K; k0 += 64) {
    __syncthreads();
    // A: 128 rows x 8 chunks = 1024 chunks over 512 threads (2 iters)
#pragma unroll
    for (int p = 0; p < 2; ++p) {
      const int c = p * 512 + tid;
      const int row = c >> 3, kc = c & 7;
      const int src = kc ^ (row & 7);       // inverse-swizzled global chunk
      __builtin_amdgcn_global_load_lds(
          (const __attribute__((address_space(1))) void*)&A[(size_t)(m0 + row) * K + k0 + src * 8],
          (__attribute__((address_space(3))) void*)&As[c * 8], 16, 0, 0);
    }
    // B: 64 rows x 8 chunks = 512 chunks over 512 threads (1 iter)
    {
      const int c = tid;
      const int row = c >> 3, kc = c & 7;
      const int src = kc ^ (row & 7);
      __builtin_amdgcn_global_load_lds(
          (const __attribute__((address_space(1))) void*)&BT[(size_t)(n0 + row) * K + k0 + src * 8],
          (__attribute__((address_space(3))) void*)&Bs[c * 8], 16, 0, 0);
    }
    __syncthreads();

    // wave computes rows [wave*16, +16) x all 64 cols; logical chunk c -> phys c^s8
    const int ca0 = (quad ^ s8) * 8;        // k-chunk quad   (k in [0,32))
    const int ca1 = ((quad | 4) ^ s8) * 8;  // k-chunk quad+4 (k in [32,64))
    bf16x8 a0 = *(const bf16x8*)&As[(wave * 16 + l16) * 64 + ca0];
    bf16x8 a1 = *(const bf16x8*)&As[(wave * 16 + l16) * 64 + ca1];
#pragma unroll
    for (int nt = 0; nt < 4; ++nt) {
      bf16x8 b0 = *(const bf16x8*)&Bs[(nt * 16 + l16) * 64 + ca0];
      bf16x8 b1 = *(const bf16x8*)&Bs[(nt * 16 + l16) * 64 + ca1];
      acc[nt] = __builtin_amdgcn_mfma_f32_16x16x32_bf16(a0, b0, acc[nt], 0, 0, 0);
      acc[nt] = __builtin_amdgcn_mfma_f32_16x16x32_bf16(a1, b1, acc[nt], 0, 0, 0);
    }
  }

  // C/D: col = l16, row = quad*4 + r
#pragma unroll
  for (int nt = 0; nt < 4; ++nt) {
    const int col = n0 + nt * 16 + l16;
    const float bv = bias[col];
#pragma unroll
    for (int r = 0; r < 4; ++r) {
      const int row = m0 + wave * 16 + quad * 4 + r;
      C[(size_t)row * N + col] = acc[nt][r] + bv;
    }
  }
}

// ---------- flash attention v14: split-st + native v_exp_f32 softmax ----------
__global__ __launch_bounds__(512, 4) void attn(const __bf16* __restrict__ Qp,
                                               const __bf16* __restrict__ Kp,
                                               const __bf16* __restrict__ Vp,
                                               __bf16* __restrict__ Out) {
  __shared__ __align__(16) __bf16 smem[32768];   // K tiles [0,16384), V tiles [16384,32768)

  const int tid  = threadIdx.x;
  const int wave = tid >> 6, lane = tid & 63;
  const int l32  = lane & 31, hi = lane >> 5;
  const int grp  = wave >> 2, sub = wave & 3;    // kv-group, q-subtile
  const int gtid = tid & 255;
  const int bhx = blockIdx.x, qt = blockIdx.y;
  const int h = bhx & (H_ - 1), b = bhx >> 4;
  const size_t bh = (size_t)b * H_ + h;
  const __bf16* kb  = Kp + bh * (L_ * 64);
  const __bf16* vb0 = Vp + bh * (L_ * 64);
  const int q0 = qt * 128 + sub * 32;
  const int sw = l32 & 7;

  // Hoisted per-lane LDS base pointers; one per k-chunk class x=0..3.
  const __bf16* kbase[4];
#pragma unroll
  for (int x = 0; x < 4; ++x)
    kbase[x] = smem + grp * 8192 + l32 * 64 + ((((x * 2 + hi) ^ sw)) << 3);

  // Q fragments: B-operand of 32x32x16 (col=q=l32, k-elems = hi*8+j)
  bf16x8 qf[4];
#pragma unroll
  for (int ks = 0; ks < 4; ++ks)
    qf[ks] = *(const bf16x8*)&Qp[(bh * L_ + q0 + l32) * 64 + ks * 16 + hi * 8];

  f32x16 o[2];
#pragma unroll
  for (int dh = 0; dh < 2; ++dh)
#pragma unroll
    for (int r = 0; r < 16; ++r) o[dh][r] = 0.f;
  f32x2 lp2 = (f32x2){0.f, 0.f};

#define STAGE(g, buf, kt)                                                       \
  {                                                                             \
    _Pragma("unroll")                                                           \
    for (int p = 0; p < 2; ++p) {                                               \
      const int c = p * 256 + gtid;                                             \
      __builtin_amdgcn_global_load_lds(                                         \
          (const __attribute__((address_space(1))) void*)(kb + (size_t)(kt) * 4096 + c * 8), \
          (__attribute__((address_space(3))) void*)&smem[((g) * 2 + (buf)) * 4096 + c * 8], 16, 0, 0); \
      __builtin_amdgcn_global_load_lds(                                         \
          (const __attribute__((address_space(1))) void*)(vb0 + (size_t)(kt) * 4096 + c * 8), \
          (__attribute__((address_space(3))) void*)&smem[16384 + ((g) * 2 + (buf)) * 4096 + c * 8], 16, 0, 0); \
    }                                                                           \
  }

// Fixed-max softmax + pack to bf16 + cross-half redistribute into PV A-frags.
#define SMAX(STV, PB)                                                           \
  {                                                                             \
    float p_[16];                                                               \
    _Pragma("unroll")                                                           \
    for (int r = 0; r < 16; ++r) p_[r] = EXP2(STV[r]);                          \
    _Pragma("unroll")                                                           \
    for (int i = 0; i < 8; ++i) {                                               \
      f32x2 t_; t_[0] = p_[2 * i]; t_[1] = p_[2 * i + 1];                       \
      lp2 += t_;                                                                \
    }                                                                           \
    int w_[8];                                                                  \
    _Pragma("unroll")                                                           \
    for (int i = 0; i < 8; ++i)                                                 \
      asm volatile("v_cvt_pk_bf16_f32 %0, %1, %2"                               \
                   : "=v"(w_[i]) : "v"(p_[2 * i]), "v"(p_[2 * i + 1]));         \
    asm volatile("v_permlane32_swap_b32 %0, %1" : "+v"(w_[0]), "+v"(w_[2]));    \
    asm volatile("v_permlane32_swap_b32 %0, %1" : "+v"(w_[1]), "+v"(w_[3]));    \
    asm volatile("v_permlane32_swap_b32 %0, %1" : "+v"(w_[4]), "+v"(w_[6]));    \
    asm volatile("v_permlane32_swap_b32 %0, %1" : "+v"(w_[5]), "+v"(w_[7]));    \
    union { int i4[4]; bf16x8 v; } u0_, u1_;                                    \
    u0_.i4[0] = w_[0]; u0_.i4[1] = w_[1]; u0_.i4[2] = w_[2]; u0_.i4[3] = w_[3]; \
    u1_.i4[0] = w_[4]; u1_.i4[1] = w_[5]; u1_.i4[2] = w_[6]; u1_.i4[3] = w_[7]; \
    pa[PB] = u0_.v; pa[PB + 1] = u1_.v;                                         \
  }

// One 64-key tile, compile-time buffer index CUR. Split-st schedule: st0's
// QK+SMAX completes (st0 dead) before st1 is computed -> one live f32x16.
#define BODY(CUR, T, DOSTAGE)                                                   \
  {                                                                             \
    if (DOSTAGE) STAGE(grp, (CUR) ^ 1, 2 * ((T) + 1) + grp)                     \
    bf16x8 pa[4];                                                               \
    {                                                                           \
      f32x16 st0;                                                               \
      _Pragma("unroll")                                                         \
      for (int r = 0; r < 16; ++r) st0[r] = 0.f;                                \
      __builtin_amdgcn_s_setprio(1);                                            \
      _Pragma("unroll")                                                         \
      for (int ks = 0; ks < 4; ++ks) {                                          \
        const bf16x8 k0 = *(const bf16x8*)(kbase[ks] + (CUR) * 4096);           \
        st0 = __builtin_amdgcn_mfma_f32_32x32x16_bf16(k0, qf[ks], st0, 0, 0, 0); \
      }                                                                         \
      __builtin_amdgcn_s_setprio(0);                                            \
      SMAX(st0, 0)                                                              \
    }                                                                           \
    {                                                                           \
      f32x16 st1;                                                               \
      _Pragma("unroll")                                                         \
      for (int r = 0; r < 16; ++r) st1[r] = 0.f;                                \
      __builtin_amdgcn_s_setprio(1);                                            \
      _Pragma("unroll")                                                         \
      for (int ks = 0; ks < 4; ++ks) {                                          \
        const bf16x8 k1 = *(const bf16x8*)(kbase[ks] + (CUR) * 4096 + 2048);    \
        st1 = __builtin_amdgcn_mfma_f32_32x32x16_bf16(k1, qf[ks], st1, 0, 0, 0); \
      }                                                                         \
      __builtin_amdgcn_s_setprio(0);                                            \
      SMAX(st1, 2)                                                              \
    }                                                                           \
    __builtin_amdgcn_s_setprio(1);                                              \
    _Pragma("unroll")                                                           \
    for (int kp = 0; kp < 4; ++kp) {                                            \
      const bf16x8 v0 = *(const bf16x8*)(kbase[kp] + 16384 + (CUR) * 4096);     \
      const bf16x8 v1 = *(const bf16x8*)(kbase[kp] + 16384 + (CUR) * 4096 + 2048); \
      o[0] = __builtin_amdgcn_mfma_f32_32x32x16_bf16(pa[kp], v0, o[0], 0, 0, 0); \
      o[1] = __builtin_amdgcn_mfma_f32_32x32x16_bf16(pa[kp], v1, o[1], 0, 0, 0); \
    }                                                                           \
    __builtin_amdgcn_s_setprio(0);                                              \
    __syncthreads();                                                            \
  }

  STAGE(grp, 0, grp)
  __syncthreads();

#pragma unroll 1
  for (int tt = 0; tt < 7; ++tt) {
    BODY(0, 2 * tt, true)
    BODY(1, 2 * tt + 1, true)
  }
  BODY(0, 14, true)
  BODY(1, 15, false)

  // ---- epilogue: combine kv-groups through LDS (stride-34 f32x2: 2-way max
  // bank aliasing = free), normalize, store ----
  float lpart = lp2[0] + lp2[1];
  lpart += __shfl_xor(lpart, 32);          // full l[q=l32] for this group

  float* fs = (float*)smem;                // [sub][lane][16 f32x2 @ stride 34]
  float* fl = fs + 8704;                   // l partials: [grp][sub][32]

  if (grp == 1) {
#pragma unroll
    for (int dh = 0; dh < 2; ++dh)
#pragma unroll
      for (int j2 = 0; j2 < 8; ++j2) {
        f32x2 tv; tv[0] = o[dh][j2 * 2]; tv[1] = o[dh][j2 * 2 + 1];
        *(f32x2*)&fs[sub * 2176 + lane * 34 + (dh * 8 + j2) * 2] = tv;
      }
    if (hi == 0) fl[128 + sub * 32 + l32] = lpart;
  } else {
    if (hi == 0) fl[sub * 32 + l32] = lpart;
  }
  __syncthreads();
  if (grp == 1) return;

  float linv[16];                          // q = (k&3) + 8*(k>>2) + 4*hi
#pragma unroll
  for (int rq = 0; rq < 4; ++rq) {
    const f32x4 a = *(const f32x4*)&fl[sub * 32 + rq * 8 + 4 * hi];
    const f32x4 c = *(const f32x4*)&fl[128 + sub * 32 + rq * 8 + 4 * hi];
#pragma unroll
    for (int e = 0; e < 4; ++e) linv[rq * 4 + e] = 1.0f / (a[e] + c[e]);
  }

#pragma unroll
  for (int dh = 0; dh < 2; ++dh)
#pragma unroll
    for (int j2 = 0; j2 < 8; ++j2) {
      const f32x2 r = *(const f32x2*)&fs[sub * 2176 + lane * 34 + (dh * 8 + j2) * 2];
#pragma unroll
      for (int e2 = 0; e2 < 2; ++e2) {
        const int k = j2 * 2 + e2;
        const float val = (o[dh][k] + r[e2]) * linv[k];
        const int q = (k & 3) + 8 * (k >> 2) + 4 * hi;
        Out[((size_t)b * L_ + q0 + q) * D_ + h * 64 + dh * 32 + l32] = f2bf(val);
      }
    }
#undef STAGE
#undef SMAX
#undef BODY
}

extern "C" void kernel_launch(void* const* d_in, const int* in_sizes, int n_in,
                              void* d_out, int out_size, void* d_ws, size_t ws_size,
                              hipStream_t stream) {
  (void)in_sizes; (void)n_in; (void)out_size; (void)ws_size;
  const float* x     = (const float*)d_in[0];
  const float* w_qkv = (const float*)d_in[1];
  const float* b_qkv = (const float*)d_in[2];
  const float* w_out = (const float*)d_in[3];
  const float* b_out = (const float*)d_in[4];
  float* out = (float*)d_out;

  const size_t NT = (size_t)B_ * L_;              // 4096 tokens
  const size_t PHD = (size_t)B_ * H_ * L_ * 64;   // packed per-head tensor
  __bf16* att   = (__bf16*)d_ws;                  // [4096,1024] bf16
  __bf16* xb    = att + NT * D_;                  // [4096,1024] bf16
  __bf16* wqkvT = xb + NT * D_;                   // [3072,1024] bf16
  __bf16* woutT = wqkvT + (size_t)3 * D_ * D_;    // [1024,1024] bf16
  __bf16* Qp    = woutT + (size_t)D_ * D_;        // packed Q (pre-scaled)
  __bf16* Kp    = Qp + PHD;                       // packed K (swizzled)
  __bf16* Vp    = Kp + PHD;                       // packed V^T (tiled, swizzled)

  // fused conversions (x cvt + both weight transposes)
  prep<<<dim3(6144), dim3(256), 0, stream>>>(x, w_qkv, w_out, xb, wqkvT, woutT);
  // QKV projection -> packed per-head Q/K/V, BK=64 + conflict-free swizzle
  gemm_qkv<<<dim3(3 * D_ / 128, NT / 128), dim3(256), 0, stream>>>(
      xb, wqkvT, b_qkv, Qp, Kp, Vp, (int)NT, 3 * D_, D_);
  // attention v14 (native exp2)
  attn<<<dim3(B_ * H_, L_ / 128), dim3(512), 0, stream>>>(Qp, Kp, Vp, att);
  // output projection: 128x64 tiles, 512 thr (R13: half the staging/barrier
  // cost per FLOP at unchanged 16 waves/CU)
  gemm_bt64<<<dim3(D_ / 64, NT / 128), dim3(512), 0, stream>>>(
      att, woutT, b_out, out, (int)NT, D_, D_);
}

// Round 14
// 170.941 us; speedup vs baseline: 1.0142x; 1.0142x over previous
//
#include <hip/hip_runtime.h>
#include <hip/hip_bf16.h>

typedef __bf16 bf16x8 __attribute__((ext_vector_type(8)));
typedef __bf16 bf16x4 __attribute__((ext_vector_type(4)));
typedef float f32x2 __attribute__((ext_vector_type(2)));
typedef float f32x4 __attribute__((ext_vector_type(4)));
typedef float f32x16 __attribute__((ext_vector_type(16)));

#define B_ 2
#define L_ 2048
#define D_ 1024
#define H_ 16
#define DK_ 64

// 0.125 (1/sqrt(DK)) * log2(e): folded into Q so P = exp2(S^T) directly.
#define QSCALE 0.180336880f

// Raw HW exp2 (R12: -14.3us on attn — OCML fixup was the hidden VALU mass).
#if __has_builtin(__builtin_amdgcn_exp2f)
#define EXP2(x) __builtin_amdgcn_exp2f(x)
#else
extern "C" __device__ float __ocml_native_exp2_f32(float);
#define EXP2(x) __ocml_native_exp2_f32(x)
#endif

__device__ __forceinline__ __bf16 f2bf(float f) { return (__bf16)f; }

// ---------- fused prep: x->bf16, w_qkv->T bf16, w_out->T bf16 ----------
__global__ __launch_bounds__(256) void prep(const float* __restrict__ x,
                                            const float* __restrict__ w_qkv,
                                            const float* __restrict__ w_out,
                                            __bf16* __restrict__ xb,
                                            __bf16* __restrict__ wqkvT,
                                            __bf16* __restrict__ woutT) {
  __shared__ float ts[32][33];
  const int blk = blockIdx.x;
  const int tid = threadIdx.x;
  if (blk < 2048) {
    const int i = blk * 2048 + tid * 8;
    const float4 a = *(const float4*)&x[i];
    const float4 b = *(const float4*)&x[i + 4];
    bf16x8 o;
    o[0] = f2bf(a.x); o[1] = f2bf(a.y); o[2] = f2bf(a.z); o[3] = f2bf(a.w);
    o[4] = f2bf(b.x); o[5] = f2bf(b.y); o[6] = f2bf(b.z); o[7] = f2bf(b.w);
    *(bf16x8*)&xb[i] = o;
    return;
  }
  const float* W;
  __bf16* WT;
  int N, t;
  if (blk < 5120) { t = blk - 2048; N = 3 * D_; W = w_qkv; WT = wqkvT; }
  else            { t = blk - 5120; N = D_;     W = w_out; WT = woutT; }
  const int nblk = N / 32;
  const int nt = (t % nblk) * 32, kt = (t / nblk) * 32;
  const int K = D_;
  const int r = tid >> 3, c4 = (tid & 7) * 4;
  const float4 v = *(const float4*)&W[(size_t)(kt + r) * N + nt + c4];
  ts[r][c4 + 0] = v.x; ts[r][c4 + 1] = v.y; ts[r][c4 + 2] = v.z; ts[r][c4 + 3] = v.w;
  __syncthreads();
  bf16x4 o;
  o[0] = f2bf(ts[c4 + 0][r]); o[1] = f2bf(ts[c4 + 1][r]);
  o[2] = f2bf(ts[c4 + 2][r]); o[3] = f2bf(ts[c4 + 3][r]);
  *(bf16x4*)&WT[(size_t)(nt + r) * K + kt + c4] = o;
}

// ---------- m97-style GEMM (QKV): C = A @ BT^T + bias, split epilogue ----------
// 128x128 tile, BK=64 + T2 source-side XOR swizzle (conflict-free frag reads).
__global__ __launch_bounds__(256) void gemm_qkv(const __bf16* __restrict__ A,
                                                const __bf16* __restrict__ BT,
                                                const float* __restrict__ bias,
                                                __bf16* __restrict__ Qp,
                                                __bf16* __restrict__ Kp,
                                                __bf16* __restrict__ Vp,
                                                int M, int N, int K) {
  __shared__ __align__(16) __bf16 smem_bf[17408];

  const int tid  = threadIdx.x;
  const int wave = tid >> 6, lane = tid & 63, quad = lane >> 4, l16 = lane & 15;
  const int wr = wave >> 1, wc = wave & 1;
  const int m0 = blockIdx.y * 128, n0 = blockIdx.x * 128;
  const int s8 = l16 & 7;                 // frag-row swizzle key (row&7 == l16&7)

  f32x4 acc[4][4];
#pragma unroll
  for (int i = 0; i < 4; ++i)
#pragma unroll
    for (int j = 0; j < 4; ++j) acc[i][j] = (f32x4){0.f, 0.f, 0.f, 0.f};

  for (int k0 = 0; k0 < K; k0 += 64) {
    __syncthreads();
#pragma unroll
    for (int p = 0; p < 4; ++p) {
      const int c = p * 256 + tid;          // 1024 chunks of 16B per tile
      const int row = c >> 3, kc = c & 7;   // 8 chunks per 128B row
      const int src = kc ^ (row & 7);       // inverse-swizzled global chunk
      __builtin_amdgcn_global_load_lds(
          (const __attribute__((address_space(1))) void*)&A[(size_t)(m0 + row) * K + k0 + src * 8],
          (__attribute__((address_space(3))) void*)&smem_bf[c * 8], 16, 0, 0);
      __builtin_amdgcn_global_load_lds(
          (const __attribute__((address_space(1))) void*)&BT[(size_t)(n0 + row) * K + k0 + src * 8],
          (__attribute__((address_space(3))) void*)&smem_bf[8192 + c * 8], 16, 0, 0);
    }
    __syncthreads();

#pragma unroll
    for (int ks = 0; ks < 2; ++ks) {
      const int ca = ((ks * 4 + quad) ^ s8) << 3;   // physical chunk offset
      bf16x8 af[4], bfr[4];
#pragma unroll
      for (int mt = 0; mt < 4; ++mt)
        af[mt] = *(const bf16x8*)&smem_bf[(wr * 64 + mt * 16 + l16) * 64 + ca];
#pragma unroll
      for (int nt = 0; nt < 4; ++nt)
        bfr[nt] = *(const bf16x8*)&smem_bf[8192 + (wc * 64 + nt * 16 + l16) * 64 + ca];
#pragma unroll
      for (int mt = 0; mt < 4; ++mt)
#pragma unroll
        for (int nt = 0; nt < 4; ++nt)
          acc[mt][nt] = __builtin_amdgcn_mfma_f32_16x16x32_bf16(af[mt], bfr[nt], acc[mt][nt], 0, 0, 0);
    }
  }

  const int sec  = (n0 + wc * 64) >> 6;   // 64-col section, 0..47
  const int type = sec % 3;               // 0=Q, 1=K, 2=V
  const int hh   = sec / 3;               // head
  const int row0 = m0 + wr * 64;
  const int bb   = row0 >> 11;
  const int tok0 = row0 & (L_ - 1);
  const size_t bh = (size_t)bb * H_ + hh;
  float bvv[4];
#pragma unroll
  for (int nt = 0; nt < 4; ++nt) bvv[nt] = bias[n0 + wc * 64 + nt * 16 + l16];

  __syncthreads();                        // all waves done reading As/Bs
  __bf16* epi = smem_bf + wave * 4352;    // 64 rows x 68 elems, per-wave

  if (type == 2) {
#pragma unroll
    for (int nt = 0; nt < 4; ++nt) {
      const int d = nt * 16 + l16;
#pragma unroll
      for (int mt = 0; mt < 4; ++mt) {
        bf16x4 t;
#pragma unroll
        for (int r = 0; r < 4; ++r) t[r] = f2bf(acc[mt][nt][r] + bvv[nt]);
        *(bf16x4*)&epi[d * 68 + mt * 16 + quad * 4] = t;
      }
    }
  } else {
    const float sc = (type == 0) ? QSCALE : 1.0f;
#pragma unroll
    for (int nt = 0; nt < 4; ++nt)
#pragma unroll
      for (int mt = 0; mt < 4; ++mt)
#pragma unroll
        for (int r = 0; r < 4; ++r)
          epi[(mt * 16 + quad * 4 + r) * 68 + nt * 16 + l16] =
              f2bf((acc[mt][nt][r] + bvv[nt]) * sc);
  }
  asm volatile("s_waitcnt lgkmcnt(0)" ::: "memory");

  __bf16* dst = (type == 0 ? Qp : type == 1 ? Kp : Vp) + (bh * L_ + tok0) * 64;
  const int swzm = (type == 0) ? 0 : 7;
#pragma unroll
  for (int i = 0; i < 8; ++i) {
    const int c = i * 64 + lane;
    const int row = c >> 3, cc = c & 7;
    const int gcc = cc ^ (row & swzm);
    const __bf16* lp = epi + row * 68 + cc * 8;
    int2 lo = *(const int2*)lp;
    int2 hi = *(const int2*)(lp + 4);
    int4 v; v.x = lo.x; v.y = lo.y; v.z = hi.x; v.w = hi.y;
    *(int4*)(dst + (size_t)row * 64 + gcc * 8) = v;
  }
}

// ---------- output-projection GEMM: 64x64 tile, BK=64, T2 XOR swizzle ----------
// (R12-best: 1024 blocks = 4/CU, conflict-free reads.)
__global__ __launch_bounds__(256) void gemm_bt64(const __bf16* __restrict__ A,
                                                 const __bf16* __restrict__ BT,
                                                 const float* __restrict__ bias,
                                                 float* __restrict__ C,
                                                 int M, int N, int K) {
  __shared__ __align__(16) __bf16 As[64 * 64];   // [m][k], chunk-swizzled
  __shared__ __align__(16) __bf16 Bs[64 * 64];   // [n][k], chunk-swizzled

  const int tid  = threadIdx.x;
  const int wave = tid >> 6, lane = tid & 63, quad = lane >> 4, l16 = lane & 15;
  const int m0 = blockIdx.y * 64, n0 = blockIdx.x * 64;
  const int s8 = l16 & 7;                 // read-row swizzle key (rows = x*16+l16)

  f32x4 acc[4];
  acc[0] = acc[1] = acc[2] = acc[3] = (f32x4){0.f, 0.f, 0.f, 0.f};

  for (int k0 = 0; k0 < K; k0 += 64) {
    __syncthreads();
#pragma unroll
    for (int p = 0; p < 2; ++p) {
      const int c = p * 256 + tid;          // 512 chunks of 16B per tensor
      const int row = c >> 3, kc = c & 7;   // 8 chunks per 128B row
      const int src = kc ^ (row & 7);       // inverse-swizzled global chunk
      __builtin_amdgcn_global_load_lds(
          (const __attribute__((address_space(1))) void*)&A[(size_t)(m0 + row) * K + k0 + src * 8],
          (__attribute__((address_space(3))) void*)&As[c * 8], 16, 0, 0);
      __builtin_amdgcn_global_load_lds(
          (const __attribute__((address_space(1))) void*)&BT[(size_t)(n0 + row) * K + k0 + src * 8],
          (__attribute__((address_space(3))) void*)&Bs[c * 8], 16, 0, 0);
    }
    __syncthreads();

    // wave computes rows [wave*16, +16) x all 64 cols; logical chunk c -> phys c^s8
    const int ca0 = (quad ^ s8) * 8;        // k-chunk quad   (k in [0,32))
    const int ca1 = ((quad | 4) ^ s8) * 8;  // k-chunk quad+4 (k in [32,64))
    bf16x8 a0 = *(const bf16x8*)&As[(wave * 16 + l16) * 64 + ca0];
    bf16x8 a1 = *(const bf16x8*)&As[(wave * 16 + l16) * 64 + ca1];
#pragma unroll
    for (int nt = 0; nt < 4; ++nt) {
      bf16x8 b0 = *(const bf16x8*)&Bs[(nt * 16 + l16) * 64 + ca0];
      bf16x8 b1 = *(const bf16x8*)&Bs[(nt * 16 + l16) * 64 + ca1];
      acc[nt] = __builtin_amdgcn_mfma_f32_16x16x32_bf16(a0, b0, acc[nt], 0, 0, 0);
      acc[nt] = __builtin_amdgcn_mfma_f32_16x16x32_bf16(a1, b1, acc[nt], 0, 0, 0);
    }
  }

  // C/D: col = l16, row = quad*4 + r
#pragma unroll
  for (int nt = 0; nt < 4; ++nt) {
    const int col = n0 + nt * 16 + l16;
    const float bv = bias[col];
#pragma unroll
    for (int r = 0; r < 4; ++r) {
      const int row = m0 + wave * 16 + quad * 4 + r;
      C[(size_t)row * N + col] = acc[nt][r] + bv;
    }
  }
}

// ---------- flash attention v15: 64 q-rows per wave (halved LDS-port traffic) ----------
// R13 budget closure: attn is LDS-port-bound (16 waves/CU x 16 ds_read_b128
// x ~10cyc + conflicts ~ 4.5k cyc/BODY-round >> issue). Fix: each wave owns
// TWO 32-q subtiles (qh=0,1) so every K/V fragment read feeds 2 MFMAs ->
// LDS reads per q*k unit halve. Grid (32 bh, 8 qt) = 256 blocks x 8 waves
// (2 kv-grps x 4 subs x 64q). ~190 VGPR -> 2 waves/SIMD (launch_bounds 512,2).
// Epilogue combines grps via LDS in 2 passes (32KB each). Math unchanged.
__global__ __launch_bounds__(512, 2) void attn(const __bf16* __restrict__ Qp,
                                               const __bf16* __restrict__ Kp,
                                               const __bf16* __restrict__ Vp,
                                               __bf16* __restrict__ Out) {
  __shared__ __align__(16) __bf16 smem[32768];   // K tiles [0,16384), V tiles [16384,32768)

  const int tid  = threadIdx.x;
  const int wave = tid >> 6, lane = tid & 63;
  const int l32  = lane & 31, hi = lane >> 5;
  const int grp  = wave >> 2, sub = wave & 3;    // kv-group, q-subtile
  const int gtid = tid & 255;
  const int bhx = blockIdx.x, qt = blockIdx.y;
  const int h = bhx & (H_ - 1), b = bhx >> 4;
  const size_t bh = (size_t)b * H_ + h;
  const __bf16* kb  = Kp + bh * (L_ * 64);
  const __bf16* vb0 = Vp + bh * (L_ * 64);
  const int q0 = qt * 256 + sub * 64;            // wave owns q-rows [q0, q0+64)
  const int sw = l32 & 7;

  // Hoisted per-lane LDS base pointers; one per k-chunk class x=0..3.
  const __bf16* kbase[4];
#pragma unroll
  for (int x = 0; x < 4; ++x)
    kbase[x] = smem + grp * 8192 + l32 * 64 + ((((x * 2 + hi) ^ sw)) << 3);

  // Q fragments for both q-halves: B-operand of 32x32x16
  bf16x8 qf[2][4];
#pragma unroll
  for (int qh = 0; qh < 2; ++qh)
#pragma unroll
    for (int ks = 0; ks < 4; ++ks)
      qf[qh][ks] = *(const bf16x8*)&Qp[(bh * L_ + q0 + qh * 32 + l32) * 64 + ks * 16 + hi * 8];

  f32x16 o[2][2];                                // [qh][dh]
#pragma unroll
  for (int qh = 0; qh < 2; ++qh)
#pragma unroll
    for (int dh = 0; dh < 2; ++dh)
#pragma unroll
      for (int r = 0; r < 16; ++r) o[qh][dh][r] = 0.f;
  f32x2 lp2[2];
  lp2[0] = (f32x2){0.f, 0.f}; lp2[1] = (f32x2){0.f, 0.f};

#define STAGE(g, buf, kt)                                                       \
  {                                                                             \
    _Pragma("unroll")                                                           \
    for (int p = 0; p < 2; ++p) {                                               \
      const int c = p * 256 + gtid;                                             \
      __builtin_amdgcn_global_load_lds(                                         \
          (const __attribute__((address_space(1))) void*)(kb + (size_t)(kt) * 4096 + c * 8), \
          (__attribute__((address_space(3))) void*)&smem[((g) * 2 + (buf)) * 4096 + c * 8], 16, 0, 0); \
      __builtin_amdgcn_global_load_lds(                                         \
          (const __attribute__((address_space(1))) void*)(vb0 + (size_t)(kt) * 4096 + c * 8), \
          (__attribute__((address_space(3))) void*)&smem[16384 + ((g) * 2 + (buf)) * 4096 + c * 8], 16, 0, 0); \
    }                                                                           \
  }

// Fixed-max softmax + pack to bf16 + cross-half redistribute into PV A-frags.
#define SMAX(STV, LP, PA, PB)                                                   \
  {                                                                             \
    float p_[16];                                                               \
    _Pragma("unroll")                                                           \
    for (int r = 0; r < 16; ++r) p_[r] = EXP2(STV[r]);                          \
    _Pragma("unroll")                                                           \
    for (int i = 0; i < 8; ++i) {                                               \
      f32x2 t_; t_[0] = p_[2 * i]; t_[1] = p_[2 * i + 1];                       \
      LP += t_;                                                                 \
    }                                                                           \
    int w_[8];                                                                  \
    _Pragma("unroll")                                                           \
    for (int i = 0; i < 8; ++i)                                                 \
      asm volatile("v_cvt_pk_bf16_f32 %0, %1, %2"                               \
                   : "=v"(w_[i]) : "v"(p_[2 * i]), "v"(p_[2 * i + 1]));         \
    asm volatile("v_permlane32_swap_b32 %0, %1" : "+v"(w_[0]), "+v"(w_[2]));    \
    asm volatile("v_permlane32_swap_b32 %0, %1" : "+v"(w_[1]), "+v"(w_[3]));    \
    asm volatile("v_permlane32_swap_b32 %0, %1" : "+v"(w_[4]), "+v"(w_[6]));    \
    asm volatile("v_permlane32_swap_b32 %0, %1" : "+v"(w_[5]), "+v"(w_[7]));    \
    union { int i4[4]; bf16x8 v; } u0_, u1_;                                    \
    u0_.i4[0] = w_[0]; u0_.i4[1] = w_[1]; u0_.i4[2] = w_[2]; u0_.i4[3] = w_[3]; \
    u1_.i4[0] = w_[4]; u1_.i4[1] = w_[5]; u1_.i4[2] = w_[6]; u1_.i4[3] = w_[7]; \
    PA[PB] = u0_.v; PA[PB + 1] = u1_.v;                                         \
  }

// One 64-key tile, compile-time buffer index CUR. Per k-half: read K frag once,
// feed BOTH q-halves (s0,s1 independent chains). PV reuses each V frag 2x.
#define BODY(CUR, T, DOSTAGE)                                                   \
  {                                                                             \
    if (DOSTAGE) STAGE(grp, (CUR) ^ 1, 2 * ((T) + 1) + grp)                     \
    bf16x8 pa0[4], pa1[4];                                                      \
    {                                                                           \
      f32x16 s0, s1;                                                            \
      _Pragma("unroll")                                                         \
      for (int r = 0; r < 16; ++r) { s0[r] = 0.f; s1[r] = 0.f; }                \
      __builtin_amdgcn_s_setprio(1);                                            \
      _Pragma("unroll")                                                         \
      for (int ks = 0; ks < 4; ++ks) {                                          \
        const bf16x8 kf = *(const bf16x8*)(kbase[ks] + (CUR) * 4096);           \
        s0 = __builtin_amdgcn_mfma_f32_32x32x16_bf16(kf, qf[0][ks], s0, 0, 0, 0); \
        s1 = __builtin_amdgcn_mfma_f32_32x32x16_bf16(kf, qf[1][ks], s1, 0, 0, 0); \
      }                                                                         \
      __builtin_amdgcn_s_setprio(0);                                            \
      SMAX(s0, lp2[0], pa0, 0)                                                  \
      SMAX(s1, lp2[1], pa1, 0)                                                  \
    }                                                                           \
    {                                                                           \
      f32x16 s0, s1;                                                            \
      _Pragma("unroll")                                                         \
      for (int r = 0; r < 16; ++r) { s0[r] = 0.f; s1[r] = 0.f; }                \
      __builtin_amdgcn_s_setprio(1);                                            \
      _Pragma("unroll")                                                         \
      for (int ks = 0; ks < 4; ++ks) {                                          \
        const bf16x8 kf = *(const bf16x8*)(kbase[ks] + (CUR) * 4096 + 2048);    \
        s0 = __builtin_amdgcn_mfma_f32_32x32x16_bf16(kf, qf[0][ks], s0, 0, 0, 0); \
        s1 = __builtin_amdgcn_mfma_f32_32x32x16_bf16(kf, qf[1][ks], s1, 0, 0, 0); \
      }                                                                         \
      __builtin_amdgcn_s_setprio(0);                                            \
      SMAX(s0, lp2[0], pa0, 2)                                                  \
      SMAX(s1, lp2[1], pa1, 2)                                                  \
    }                                                                           \
    __builtin_amdgcn_s_setprio(1);                                              \
    _Pragma("unroll")                                                           \
    for (int kp = 0; kp < 4; ++kp) {                                            \
      const bf16x8 v0 = *(const bf16x8*)(kbase[kp] + 16384 + (CUR) * 4096);     \
      const bf16x8 v1 = *(const bf16x8*)(kbase[kp] + 16384 + (CUR) * 4096 + 2048); \
      o[0][0] = __builtin_amdgcn_mfma_f32_32x32x16_bf16(pa0[kp], v0, o[0][0], 0, 0, 0); \
      o[0][1] = __builtin_amdgcn_mfma_f32_32x32x16_bf16(pa0[kp], v1, o[0][1], 0, 0, 0); \
      o[1][0] = __builtin_amdgcn_mfma_f32_32x32x16_bf16(pa1[kp], v0, o[1][0], 0, 0, 0); \
      o[1][1] = __builtin_amdgcn_mfma_f32_32x32x16_bf16(pa1[kp], v1, o[1][1], 0, 0, 0); \
    }                                                                           \
    __builtin_amdgcn_s_setprio(0);                                              \
    __syncthreads();                                                            \
  }

  STAGE(grp, 0, grp)
  __syncthreads();

#pragma unroll 1
  for (int tt = 0; tt < 7; ++tt) {
    BODY(0, 2 * tt, true)
    BODY(1, 2 * tt + 1, true)
  }
  BODY(0, 14, true)
  BODY(1, 15, false)

  // ---- epilogue: combine kv-groups via LDS, 2 passes (one per q-half) ----
  float lpart[2];
#pragma unroll
  for (int qh = 0; qh < 2; ++qh) {
    lpart[qh] = lp2[qh][0] + lp2[qh][1];
    lpart[qh] += __shfl_xor(lpart[qh], 32);     // full l[q=l32] for this group
  }

  float* fs = (float*)smem;                // [sub][lane][16 f32x2 @ stride 34]
  float* fl = fs + 8704;                   // l partials: [grp][sub][32]

#define EPIPASS(QH)                                                             \
  {                                                                             \
    if (grp == 1) {                                                             \
      _Pragma("unroll")                                                         \
      for (int dh = 0; dh < 2; ++dh)                                            \
        _Pragma("unroll")                                                       \
        for (int j2 = 0; j2 < 8; ++j2) {                                        \
          f32x2 tv; tv[0] = o[QH][dh][j2 * 2]; tv[1] = o[QH][dh][j2 * 2 + 1];   \
          *(f32x2*)&fs[sub * 2176 + lane * 34 + (dh * 8 + j2) * 2] = tv;        \
        }                                                                       \
      if (hi == 0) fl[128 + sub * 32 + l32] = lpart[QH];                        \
    } else {                                                                    \
      if (hi == 0) fl[sub * 32 + l32] = lpart[QH];                              \
    }                                                                           \
    __syncthreads();                                                            \
    if (grp == 0) {                                                             \
      float linv[16];                          /* q = (k&3) + 8*(k>>2) + 4*hi */ \
      _Pragma("unroll")                                                         \
      for (int rq = 0; rq < 4; ++rq) {                                          \
        const f32x4 a = *(const f32x4*)&fl[sub * 32 + rq * 8 + 4 * hi];         \
        const f32x4 c = *(const f32x4*)&fl[128 + sub * 32 + rq * 8 + 4 * hi];   \
        _Pragma("unroll")                                                       \
        for (int e = 0; e < 4; ++e) linv[rq * 4 + e] = 1.0f / (a[e] + c[e]);    \
      }                                                                         \
      _Pragma("unroll")                                                         \
      for (int dh = 0; dh < 2; ++dh)                                            \
        _Pragma("unroll")                                                       \
        for (int j2 = 0; j2 < 8; ++j2) {                                        \
          const f32x2 r = *(const f32x2*)&fs[sub * 2176 + lane * 34 + (dh * 8 + j2) * 2]; \
          _Pragma("unroll")                                                     \
          for (int e2 = 0; e2 < 2; ++e2) {                                      \
            const int k = j2 * 2 + e2;                                          \
            const float val = (o[QH][dh][k] + r[e2]) * linv[k];                 \
            const int q = (k & 3) + 8 * (k >> 2) + 4 * hi;                      \
            Out[((size_t)b * L_ + q0 + (QH) * 32 + q) * D_ + h * 64 + dh * 32 + l32] = f2bf(val); \
          }                                                                     \
        }                                                                       \
    }                                                                           \
  }

  EPIPASS(0)
  __syncthreads();                        // pass-0 reads done before pass-1 writes
  EPIPASS(1)
#undef STAGE
#undef SMAX
#undef BODY
#undef EPIPASS
}

extern "C" void kernel_launch(void* const* d_in, const int* in_sizes, int n_in,
                              void* d_out, int out_size, void* d_ws, size_t ws_size,
                              hipStream_t stream) {
  (void)in_sizes; (void)n_in; (void)out_size; (void)ws_size;
  const float* x     = (const float*)d_in[0];
  const float* w_qkv = (const float*)d_in[1];
  const float* b_qkv = (const float*)d_in[2];
  const float* w_out = (const float*)d_in[3];
  const float* b_out = (const float*)d_in[4];
  float* out = (float*)d_out;

  const size_t NT = (size_t)B_ * L_;              // 4096 tokens
  const size_t PHD = (size_t)B_ * H_ * L_ * 64;   // packed per-head tensor
  __bf16* att   = (__bf16*)d_ws;                  // [4096,1024] bf16
  __bf16* xb    = att + NT * D_;                  // [4096,1024] bf16
  __bf16* wqkvT = xb + NT * D_;                   // [3072,1024] bf16
  __bf16* woutT = wqkvT + (size_t)3 * D_ * D_;    // [1024,1024] bf16
  __bf16* Qp    = woutT + (size_t)D_ * D_;        // packed Q (pre-scaled)
  __bf16* Kp    = Qp + PHD;                       // packed K (swizzled)
  __bf16* Vp    = Kp + PHD;                       // packed V^T (tiled, swizzled)

  // fused conversions (x cvt + both weight transposes)
  prep<<<dim3(6144), dim3(256), 0, stream>>>(x, w_qkv, w_out, xb, wqkvT, woutT);
  // QKV projection -> packed per-head Q/K/V, BK=64 + conflict-free swizzle
  gemm_qkv<<<dim3(3 * D_ / 128, NT / 128), dim3(256), 0, stream>>>(
      xb, wqkvT, b_qkv, Qp, Kp, Vp, (int)NT, 3 * D_, D_);
  // attention v15: 64 q-rows per wave, grid (32 bh, 8 qt)
  attn<<<dim3(B_ * H_, L_ / 256), dim3(512), 0, stream>>>(Qp, Kp, Vp, att);
  // output projection: 64x64 tiles, BK=64, conflict-free swizzled reads (R12 best)
  gemm_bt64<<<dim3(D_ / 64, NT / 64), dim3(256), 0, stream>>>(
      att, woutT, b_out, out, (int)NT, D_, D_);
}